// Round 1
// baseline (114.437 us; speedup 1.0000x reference)
//
#include <hip/hip_runtime.h>

// Additive RQ kernel: covar[i,j] = os * sum_d (1 + ((x_i,d - x_j,d)/l_d)^2 / (2a))^(-a)
// Output layout: [ mean (N floats, zeros) | covar (N*N floats) ]

#define D 32
#define TILE 32

__global__ __launch_bounds__(256) void zero_mean_kernel(float* __restrict__ out, int n) {
    int i = blockIdx.x * blockDim.x + threadIdx.x;
    if (i < n) out[i] = 0.0f;
}

__global__ __launch_bounds__(256) void rq_covar_kernel(const float* __restrict__ x,
                                                       const float* __restrict__ ls,
                                                       const float* __restrict__ alpha_p,
                                                       const float* __restrict__ os_p,
                                                       float* __restrict__ covar,
                                                       int n) {
    // +1 pad: Bs[c][d] read has addr c*33+d -> bank (c+d)%32, conflict-free.
    __shared__ float As[TILE][TILE + 1];
    __shared__ float Bs[TILE][TILE + 1];

    const float alpha = alpha_p[0];
    const float oscale = os_p[0];
    const float inv2a = 0.5f / alpha;
    const float nalpha = -alpha;

    const int bi = blockIdx.y;  // row tile index
    const int bj = blockIdx.x;  // col tile index
    const int t = threadIdx.x;

    // Stage tiles: 32 rows x 32 floats each; 256 threads x 1 float4 per tile.
    {
        const int row = t >> 3;        // 0..31
        const int q = (t & 7) * 4;     // 0,4,...,28
        const float4 lv = *reinterpret_cast<const float4*>(&ls[q]);
        const float4 a = *reinterpret_cast<const float4*>(&x[(size_t)(bi * TILE + row) * D + q]);
        const float4 b = *reinterpret_cast<const float4*>(&x[(size_t)(bj * TILE + row) * D + q]);
        As[row][q + 0] = a.x / lv.x;
        As[row][q + 1] = a.y / lv.y;
        As[row][q + 2] = a.z / lv.z;
        As[row][q + 3] = a.w / lv.w;
        Bs[row][q + 0] = b.x / lv.x;
        Bs[row][q + 1] = b.y / lv.y;
        Bs[row][q + 2] = b.z / lv.z;
        Bs[row][q + 3] = b.w / lv.w;
    }
    __syncthreads();

    const int c = t & 31;        // column within tile
    const int r0 = t >> 5;       // 0..7

    float acc[4];
#pragma unroll
    for (int k = 0; k < 4; ++k) {
        const int r = r0 + k * 8;
        float s = 0.0f;
#pragma unroll
        for (int d = 0; d < D; ++d) {
            const float diff = As[r][d] - Bs[c][d];
            const float base = fmaf(diff * diff, inv2a, 1.0f);
            // base^(-alpha) = exp2(-alpha * log2(base)); base >= 1 always.
            s += exp2f(nalpha * __log2f(base));
        }
        acc[k] = s;
    }

#pragma unroll
    for (int k = 0; k < 4; ++k) {
        const int r = r0 + k * 8;
        covar[(size_t)(bi * TILE + r) * n + (bj * TILE + c)] = oscale * acc[k];
    }
}

extern "C" void kernel_launch(void* const* d_in, const int* in_sizes, int n_in,
                              void* d_out, int out_size, void* d_ws, size_t ws_size,
                              hipStream_t stream) {
    const float* x = (const float*)d_in[0];
    const float* ls = (const float*)d_in[1];
    const float* alpha_p = (const float*)d_in[2];
    const float* os_p = (const float*)d_in[3];

    const int n = in_sizes[0] / D;  // 2048
    float* mean_out = (float*)d_out;
    float* covar = (float*)d_out + n;

    zero_mean_kernel<<<(n + 255) / 256, 256, 0, stream>>>(mean_out, n);

    dim3 grid(n / TILE, n / TILE);
    rq_covar_kernel<<<grid, 256, 0, stream>>>(x, ls, alpha_p, os_p, covar, n);
}

// Round 3
// 81.355 us; speedup vs baseline: 1.4066x; 1.4066x over previous
//
#include <hip/hip_runtime.h>

// Additive RQ kernel, symmetric: covar[i,j] = os * sum_d (1 + ((x_i,d-x_j,d)/l_d)^2/(2a))^(-a)
// Output layout: [ mean (N floats, zeros) | covar (N*N floats) ]
// Upper-triangle 32x32 tiles only; off-diagonal tiles mirrored via LDS transpose.

#define D 32
#define TILE 32

#if __has_builtin(__builtin_amdgcn_exp2f)
#define EXP2F(x) __builtin_amdgcn_exp2f(x)
#else
#define EXP2F(x) exp2f(x)
#endif
#if __has_builtin(__builtin_amdgcn_logf)
#define LOG2F(x) __builtin_amdgcn_logf(x)
#else
#define LOG2F(x) __log2f(x)
#endif

__global__ __launch_bounds__(256) void rq_covar_sym_kernel(
    const float* __restrict__ x,
    const float* __restrict__ ls,
    const float* __restrict__ alpha_p,
    const float* __restrict__ os_p,
    float* __restrict__ mean_out,
    float* __restrict__ covar,
    int n, int ntiles)
{
    // stride 36 floats: rows 16B-aligned for float4 LDS access; broadcast reads
    // (As) are conflict-free by nature; Bs per-lane float4 reads are one-time.
    __shared__ float As[TILE][36];
    __shared__ float Bs[TILE][36];

    const int t = threadIdx.x;
    const int k = blockIdx.x;

    // fold mean zeroing into the first ceil(n/256) blocks
    {
        const int idx = k * 256 + t;
        if (idx < n) mean_out[idx] = 0.0f;
    }

    // closed-form upper-triangle decode (bi <= bj), row-major over rows bi:
    // k = bi*ntiles - bi*(bi-1)/2 + (bj - bi)
    const float nt = (float)ntiles;
    int bi = (int)(nt + 0.5f - sqrtf((nt + 0.5f) * (nt + 0.5f) - 2.0f * (float)k));
    // guard against fp rounding on the boundary
    while (bi > 0 && k < bi * ntiles - (bi * (bi - 1)) / 2) --bi;
    while (k >= (bi + 1) * ntiles - ((bi + 1) * bi) / 2) ++bi;
    const int bj = bi + (k - (bi * ntiles - (bi * (bi - 1)) / 2));

    const float alpha = alpha_p[0];
    const float oscale = os_p[0];
    const float nalpha = -alpha;
    const float rs2a = rsqrtf(2.0f * alpha);  // 1/sqrt(2*alpha)

    // Stage tiles pre-scaled by 1/(l_d * sqrt(2a)): 256 threads, one float4 per tile each.
    {
        const int row = t >> 3;        // 0..31
        const int q = (t & 7) * 4;     // 0,4,...,28
        const float4 lv = *reinterpret_cast<const float4*>(&ls[q]);
        const float4 a = *reinterpret_cast<const float4*>(&x[(size_t)(bi * TILE + row) * D + q]);
        const float4 b = *reinterpret_cast<const float4*>(&x[(size_t)(bj * TILE + row) * D + q]);
        const float w0 = rs2a / lv.x, w1 = rs2a / lv.y, w2 = rs2a / lv.z, w3 = rs2a / lv.w;
        As[row][q + 0] = a.x * w0;  Bs[row][q + 0] = b.x * w0;
        As[row][q + 1] = a.y * w1;  Bs[row][q + 1] = b.y * w1;
        As[row][q + 2] = a.z * w2;  Bs[row][q + 2] = b.z * w2;
        As[row][q + 3] = a.w * w3;  Bs[row][q + 3] = b.w * w3;
    }
    __syncthreads();

    const int c = t & 31;        // column within tile
    const int r0 = t >> 5;       // 0..7

    // B-row lives in registers for the whole kernel (loaded once).
    float bs[D];
#pragma unroll
    for (int q = 0; q < D; q += 4) {
        const float4 v = *reinterpret_cast<const float4*>(&Bs[c][q]);
        bs[q] = v.x; bs[q + 1] = v.y; bs[q + 2] = v.z; bs[q + 3] = v.w;
    }

    float acc[4];
#pragma unroll
    for (int kk = 0; kk < 4; ++kk) {
        const int r = r0 + kk * 8;
        // A-row: broadcast LDS reads into registers.
        float as[D];
#pragma unroll
        for (int q = 0; q < D; q += 4) {
            const float4 v = *reinterpret_cast<const float4*>(&As[r][q]);
            as[q] = v.x; as[q + 1] = v.y; as[q + 2] = v.z; as[q + 3] = v.w;
        }
        float s0 = 0.0f, s1 = 0.0f;
#pragma unroll
        for (int d = 0; d < D; d += 2) {
            const float diff0 = as[d] - bs[d];
            const float base0 = fmaf(diff0, diff0, 1.0f);
            s0 += EXP2F(nalpha * LOG2F(base0));
            const float diff1 = as[d + 1] - bs[d + 1];
            const float base1 = fmaf(diff1, diff1, 1.0f);
            s1 += EXP2F(nalpha * LOG2F(base1));
        }
        acc[kk] = oscale * (s0 + s1);
    }

    // direct (coalesced) write of own tile
#pragma unroll
    for (int kk = 0; kk < 4; ++kk) {
        const int r = r0 + kk * 8;
        covar[(size_t)(bi * TILE + r) * n + (bj * TILE + c)] = acc[kk];
    }

    // mirror write for off-diagonal tiles: transpose through LDS, coalesced store
    if (bi != bj) {
        __syncthreads();  // done reading As
#pragma unroll
        for (int kk = 0; kk < 4; ++kk) {
            As[r0 + kk * 8][c] = acc[kk];
        }
        __syncthreads();
#pragma unroll
        for (int kk = 0; kk < 4; ++kk) {
            const int rr = r0 + kk * 8;
            const float v = As[c][rr];
            covar[(size_t)(bj * TILE + rr) * n + (bi * TILE + c)] = v;
        }
    }
}

extern "C" void kernel_launch(void* const* d_in, const int* in_sizes, int n_in,
                              void* d_out, int out_size, void* d_ws, size_t ws_size,
                              hipStream_t stream) {
    const float* x = (const float*)d_in[0];
    const float* ls = (const float*)d_in[1];
    const float* alpha_p = (const float*)d_in[2];
    const float* os_p = (const float*)d_in[3];

    const int n = in_sizes[0] / D;       // 2048
    const int ntiles = n / TILE;         // 64
    const int nblocks = ntiles * (ntiles + 1) / 2;  // 2080

    float* mean_out = (float*)d_out;
    float* covar = (float*)d_out + n;

    rq_covar_sym_kernel<<<nblocks, 256, 0, stream>>>(x, ls, alpha_p, os_p,
                                                     mean_out, covar, n, ntiles);
}